// Round 1
// baseline (438.539 us; speedup 1.0000x reference)
//
#include <hip/hip_runtime.h>
#include <math.h>

constexpr int INDIM = 256;
constexpr int HID   = 128;
constexpr int HEADS = 4;
constexpr int HC    = HEADS * HID;   // 512

// ---------------- GEMM: C[M,N] = A[M,K] @ B[K,N] (+ optional bias) ----------------
// 64x64 tile, BK=16, 256 threads, 4x4 micro-tile per thread. f32 vector-ALU.
__global__ __launch_bounds__(256) void gemm_f32(const float* __restrict__ A,
                                                const float* __restrict__ B,
                                                const float* __restrict__ bias,
                                                float* __restrict__ C,
                                                int M, int N, int K) {
  __shared__ float As[16][64];   // As[kk][m]
  __shared__ float Bs[16][64];   // Bs[kk][n]
  const int tid = threadIdx.x;
  const int tx = tid & 15, ty = tid >> 4;
  const int row0 = blockIdx.y * 64, col0 = blockIdx.x * 64;
  float acc[4][4] = {};
  for (int kt = 0; kt < K; kt += 16) {
    {
      // A tile: 64 rows x 16 k -> one float4 per thread
      int m  = tid >> 2;
      int kg = (tid & 3) * 4;
      int row = row0 + m;
      float4 av = make_float4(0.f, 0.f, 0.f, 0.f);
      if (row < M) av = *(const float4*)&A[(size_t)row * K + kt + kg];
      As[kg + 0][m] = av.x; As[kg + 1][m] = av.y;
      As[kg + 2][m] = av.z; As[kg + 3][m] = av.w;
      // B tile: 16 k x 64 cols -> one float4 per thread (N multiple of 64)
      int kk = tid >> 4;
      int ng = (tid & 15) * 4;
      float4 bv = *(const float4*)&B[(size_t)(kt + kk) * N + col0 + ng];
      *(float4*)&Bs[kk][ng] = bv;
    }
    __syncthreads();
#pragma unroll
    for (int kk = 0; kk < 16; ++kk) {
      float4 a = *(const float4*)&As[kk][ty * 4];
      float4 b = *(const float4*)&Bs[kk][tx * 4];
      float av[4] = {a.x, a.y, a.z, a.w};
      float bv[4] = {b.x, b.y, b.z, b.w};
#pragma unroll
      for (int i = 0; i < 4; ++i)
#pragma unroll
        for (int j = 0; j < 4; ++j)
          acc[i][j] = fmaf(av[i], bv[j], acc[i][j]);
    }
    __syncthreads();
  }
  float4 bb = make_float4(0.f, 0.f, 0.f, 0.f);
  if (bias) bb = *(const float4*)&bias[col0 + tx * 4];
#pragma unroll
  for (int i = 0; i < 4; ++i) {
    int row = row0 + ty * 4 + i;
    if (row < M) {
      float4 v = make_float4(acc[i][0] + bb.x, acc[i][1] + bb.y,
                             acc[i][2] + bb.z, acc[i][3] + bb.w);
      *(float4*)&C[(size_t)row * N + col0 + tx * 4] = v;
    }
  }
}

// ---------------- per-node attention scores: s_src[n,h], s_dst[n,h] ----------------
// one block per node, one wave per head, 2 channels per lane.
__global__ __launch_bounds__(256) void scores_kernel(const float* __restrict__ h,
                                                     const float* __restrict__ att_src,
                                                     const float* __restrict__ att_dst,
                                                     float* __restrict__ s_src,
                                                     float* __restrict__ s_dst) {
  const int n = blockIdx.x;
  const int wave = threadIdx.x >> 6;
  const int lane = threadIdx.x & 63;
  const float2 hv = *(const float2*)&h[(size_t)n * HC + wave * HID + lane * 2];
  const float2 as = *(const float2*)&att_src[wave * HID + lane * 2];
  const float2 ad = *(const float2*)&att_dst[wave * HID + lane * 2];
  float ss = hv.x * as.x + hv.y * as.y;
  float sd = hv.x * ad.x + hv.y * ad.y;
#pragma unroll
  for (int off = 32; off > 0; off >>= 1) {
    ss += __shfl_down(ss, off);
    sd += __shfl_down(sd, off);
  }
  if (lane == 0) {
    s_src[n * HEADS + wave] = ss;
    s_dst[n * HEADS + wave] = sd;
  }
}

// ---------------- CSR build (by dst) ----------------
__global__ void degree_kernel(const int* __restrict__ ei, int E, int N,
                              int* __restrict__ deg) {
  int e = blockIdx.x * blockDim.x + threadIdx.x;
  int total = E + N;
  if (e >= total) return;
  int dst = (e < E) ? ei[E + e] : (e - E);   // self-loops appended
  atomicAdd(&deg[dst], 1);
}

__global__ __launch_bounds__(1024) void scan_kernel(const int* __restrict__ deg,
                                                    int* __restrict__ rowstart,
                                                    int* __restrict__ cursor, int N) {
  __shared__ int sums[1024];
  const int tid = threadIdx.x;
  const int per = (N + 1023) / 1024;
  int begin = tid * per;
  int end = begin + per; if (end > N) end = N;
  if (begin > N) begin = N;
  int s = 0;
  for (int i = begin; i < end; ++i) s += deg[i];
  sums[tid] = s;
  __syncthreads();
  for (int off = 1; off < 1024; off <<= 1) {
    int v = (tid >= off) ? sums[tid - off] : 0;
    __syncthreads();
    sums[tid] += v;
    __syncthreads();
  }
  int run = (tid == 0) ? 0 : sums[tid - 1];
  for (int i = begin; i < end; ++i) {
    rowstart[i] = run;
    cursor[i] = run;
    run += deg[i];
  }
  if (tid == 1023) rowstart[N] = sums[1023];
}

__global__ void scatter_kernel(const int* __restrict__ ei, int E, int N,
                               int* __restrict__ cursor, int* __restrict__ csr_src) {
  int e = blockIdx.x * blockDim.x + threadIdx.x;
  int total = E + N;
  if (e >= total) return;
  int src, dst;
  if (e < E) { src = ei[e]; dst = ei[E + e]; }
  else       { src = dst = e - E; }
  int pos = atomicAdd(&cursor[dst], 1);
  csr_src[pos] = src;
}

// ---------------- fused segment-softmax + aggregate + head-mean + bias + elu ---------
// one block per dst node; wave = head; 2 channels per lane; online softmax.
__global__ __launch_bounds__(256) void gat_aggregate(const float* __restrict__ h,
                                                     const float* __restrict__ s_src,
                                                     const float* __restrict__ s_dst,
                                                     const int* __restrict__ rowstart,
                                                     const int* __restrict__ csr_src,
                                                     const float* __restrict__ bias,
                                                     float* __restrict__ out,
                                                     int apply_elu) {
  const int n = blockIdx.x;
  const int wave = threadIdx.x >> 6;
  const int lane = threadIdx.x & 63;
  const int rs = rowstart[n], re = rowstart[n + 1];
  const float sd = s_dst[n * HEADS + wave];
  float m = -INFINITY, denom = 0.f;
  float accx = 0.f, accy = 0.f;
  for (int j = rs; j < re; ++j) {
    int s = csr_src[j];
    float e = s_src[s * HEADS + wave] + sd;
    e = (e > 0.f) ? e : 0.2f * e;               // leaky_relu 0.2
    const float2 hv = *(const float2*)&h[(size_t)s * HC + wave * HID + lane * 2];
    if (e > m) {
      float r = __expf(m - e);                  // exp(-inf)=0 on first edge
      denom = denom * r + 1.f;
      accx = accx * r + hv.x;
      accy = accy * r + hv.y;
      m = e;
    } else {
      float w = __expf(e - m);
      denom += w;
      accx = fmaf(w, hv.x, accx);
      accy = fmaf(w, hv.y, accy);
    }
  }
  const float inv = 1.f / (denom + 1e-16f);
  __shared__ float lds[HEADS][HID];
  lds[wave][lane * 2]     = accx * inv;
  lds[wave][lane * 2 + 1] = accy * inv;
  __syncthreads();
  if (threadIdx.x < HID) {
    int c = threadIdx.x;
    float v = 0.25f * (lds[0][c] + lds[1][c] + lds[2][c] + lds[3][c]) + bias[c];
    if (apply_elu) v = (v > 0.f) ? v : expm1f(v);
    out[(size_t)n * HID + c] = v;
  }
}

// ---------------- launch ----------------
extern "C" void kernel_launch(void* const* d_in, const int* in_sizes, int n_in,
                              void* d_out, int out_size, void* d_ws, size_t ws_size,
                              hipStream_t stream) {
  const float* x    = (const float*)d_in[0];
  const int*   ei   = (const int*)d_in[1];
  const float* W1   = (const float*)d_in[2];
  const float* as1  = (const float*)d_in[3];
  const float* ad1  = (const float*)d_in[4];
  const float* b1   = (const float*)d_in[5];
  const float* W2   = (const float*)d_in[6];
  const float* as2  = (const float*)d_in[7];
  const float* ad2  = (const float*)d_in[8];
  const float* b2   = (const float*)d_in[9];
  const float* Wout = (const float*)d_in[10];
  const float* bout = (const float*)d_in[11];
  float* out = (float*)d_out;

  const int N = in_sizes[0] / INDIM;   // 20000
  const int E = in_sizes[1] / 2;       // 320000
  const int total = E + N;

  char* p = (char*)d_ws;
  auto alloc = [&](size_t bytes) -> void* {
    void* r = (void*)p;
    p += (bytes + 255) & ~(size_t)255;
    return r;
  };
  float* h     = (float*)alloc((size_t)N * HC * 4);       // 41 MB, reused per layer
  float* ssrc  = (float*)alloc((size_t)N * HEADS * 4);
  float* sdst  = (float*)alloc((size_t)N * HEADS * 4);
  float* t1    = (float*)alloc((size_t)N * HID * 4);
  float* t2    = (float*)alloc((size_t)N * HID * 4);
  int* deg     = (int*)alloc((size_t)N * 4);
  int* rowst   = (int*)alloc(((size_t)N + 1) * 4);
  int* cursor  = (int*)alloc((size_t)N * 4);
  int* csr     = (int*)alloc((size_t)total * 4);

  // CSR build (depends only on edge_index; rebuilt every call for determinism)
  hipMemsetAsync(deg, 0, (size_t)N * 4, stream);
  degree_kernel<<<(total + 255) / 256, 256, 0, stream>>>(ei, E, N, deg);
  scan_kernel<<<1, 1024, 0, stream>>>(deg, rowst, cursor, N);
  scatter_kernel<<<(total + 255) / 256, 256, 0, stream>>>(ei, E, N, cursor, csr);

  dim3 gHC(HC / 64, (N + 63) / 64);
  dim3 gOut(HID / 64, (N + 63) / 64);

  // layer 1
  gemm_f32<<<gHC, 256, 0, stream>>>(x, W1, nullptr, h, N, HC, INDIM);
  scores_kernel<<<N, 256, 0, stream>>>(h, as1, ad1, ssrc, sdst);
  gat_aggregate<<<N, 256, 0, stream>>>(h, ssrc, sdst, rowst, csr, b1, t1, 1);
  // layer 2
  gemm_f32<<<gHC, 256, 0, stream>>>(t1, W2, nullptr, h, N, HC, HID);
  scores_kernel<<<N, 256, 0, stream>>>(h, as2, ad2, ssrc, sdst);
  gat_aggregate<<<N, 256, 0, stream>>>(h, ssrc, sdst, rowst, csr, b2, t2, 1);
  // output projection
  gemm_f32<<<gOut, 256, 0, stream>>>(t2, Wout, bout, out, N, HID, HID);
}

// Round 2
// 417.204 us; speedup vs baseline: 1.0511x; 1.0511x over previous
//
#include <hip/hip_runtime.h>
#include <math.h>

constexpr int INDIM = 256;
constexpr int HID   = 128;
constexpr int HEADS = 4;
constexpr int HC    = HEADS * HID;   // 512

// ---------------- GEMM: C[M,N] = A[M,K] @ B[K,N] (+ optional bias) ----------------
// 64x64 tile, BK=16, 256 threads, 4x4 micro-tile per thread. f32 vector-ALU.
__global__ __launch_bounds__(256) void gemm_f32(const float* __restrict__ A,
                                                const float* __restrict__ B,
                                                const float* __restrict__ bias,
                                                float* __restrict__ C,
                                                int M, int N, int K) {
  __shared__ float As[16][64];   // As[kk][m]
  __shared__ float Bs[16][64];   // Bs[kk][n]
  const int tid = threadIdx.x;
  const int tx = tid & 15, ty = tid >> 4;
  const int row0 = blockIdx.y * 64, col0 = blockIdx.x * 64;
  float acc[4][4] = {};
  for (int kt = 0; kt < K; kt += 16) {
    {
      int m  = tid >> 2;
      int kg = (tid & 3) * 4;
      int row = row0 + m;
      float4 av = make_float4(0.f, 0.f, 0.f, 0.f);
      if (row < M) av = *(const float4*)&A[(size_t)row * K + kt + kg];
      As[kg + 0][m] = av.x; As[kg + 1][m] = av.y;
      As[kg + 2][m] = av.z; As[kg + 3][m] = av.w;
      int kk = tid >> 4;
      int ng = (tid & 15) * 4;
      float4 bv = *(const float4*)&B[(size_t)(kt + kk) * N + col0 + ng];
      *(float4*)&Bs[kk][ng] = bv;
    }
    __syncthreads();
#pragma unroll
    for (int kk = 0; kk < 16; ++kk) {
      float4 a = *(const float4*)&As[kk][ty * 4];
      float4 b = *(const float4*)&Bs[kk][tx * 4];
      float av[4] = {a.x, a.y, a.z, a.w};
      float bv[4] = {b.x, b.y, b.z, b.w};
#pragma unroll
      for (int i = 0; i < 4; ++i)
#pragma unroll
        for (int j = 0; j < 4; ++j)
          acc[i][j] = fmaf(av[i], bv[j], acc[i][j]);
    }
    __syncthreads();
  }
  float4 bb = make_float4(0.f, 0.f, 0.f, 0.f);
  if (bias) bb = *(const float4*)&bias[col0 + tx * 4];
#pragma unroll
  for (int i = 0; i < 4; ++i) {
    int row = row0 + ty * 4 + i;
    if (row < M) {
      float4 v = make_float4(acc[i][0] + bb.x, acc[i][1] + bb.y,
                             acc[i][2] + bb.z, acc[i][3] + bb.w);
      *(float4*)&C[(size_t)row * N + col0 + tx * 4] = v;
    }
  }
}

// ---------------- per-node attention scores: s_src[n,h], s_dst[n,h] ----------------
__global__ __launch_bounds__(256) void scores_kernel(const float* __restrict__ h,
                                                     const float* __restrict__ att_src,
                                                     const float* __restrict__ att_dst,
                                                     float* __restrict__ s_src,
                                                     float* __restrict__ s_dst) {
  const int n = blockIdx.x;
  const int wave = threadIdx.x >> 6;
  const int lane = threadIdx.x & 63;
  const float2 hv = *(const float2*)&h[(size_t)n * HC + wave * HID + lane * 2];
  const float2 as = *(const float2*)&att_src[wave * HID + lane * 2];
  const float2 ad = *(const float2*)&att_dst[wave * HID + lane * 2];
  float ss = hv.x * as.x + hv.y * as.y;
  float sd = hv.x * ad.x + hv.y * ad.y;
#pragma unroll
  for (int off = 32; off > 0; off >>= 1) {
    ss += __shfl_down(ss, off);
    sd += __shfl_down(sd, off);
  }
  if (lane == 0) {
    s_src[n * HEADS + wave] = ss;
    s_dst[n * HEADS + wave] = sd;
  }
}

// ---------------- CSR build (by dst) ----------------
__global__ void degree_kernel(const int* __restrict__ ei, int E, int N,
                              int* __restrict__ deg) {
  int e = blockIdx.x * blockDim.x + threadIdx.x;
  int total = E + N;
  if (e >= total) return;
  int dst = (e < E) ? ei[E + e] : (e - E);
  atomicAdd(&deg[dst], 1);
}

__global__ __launch_bounds__(1024) void scan_kernel(const int* __restrict__ deg,
                                                    int* __restrict__ rowstart,
                                                    int* __restrict__ cursor, int N) {
  __shared__ int sums[1024];
  const int tid = threadIdx.x;
  const int per = (N + 1023) / 1024;
  int begin = tid * per;
  int end = begin + per; if (end > N) end = N;
  if (begin > N) begin = N;
  int s = 0;
  for (int i = begin; i < end; ++i) s += deg[i];
  sums[tid] = s;
  __syncthreads();
  for (int off = 1; off < 1024; off <<= 1) {
    int v = (tid >= off) ? sums[tid - off] : 0;
    __syncthreads();
    sums[tid] += v;
    __syncthreads();
  }
  int run = (tid == 0) ? 0 : sums[tid - 1];
  for (int i = begin; i < end; ++i) {
    rowstart[i] = run;
    cursor[i] = run;
    run += deg[i];
  }
  if (tid == 1023) rowstart[N] = sums[1023];
}

__global__ void scatter_kernel(const int* __restrict__ ei, int E, int N,
                               int* __restrict__ cursor, int* __restrict__ csr_src) {
  int e = blockIdx.x * blockDim.x + threadIdx.x;
  int total = E + N;
  if (e >= total) return;
  int src, dst;
  if (e < E) { src = ei[e]; dst = ei[E + e]; }
  else       { src = dst = e - E; }
  int pos = atomicAdd(&cursor[dst], 1);
  csr_src[pos] = src;
}

// ---------------- fused segment-softmax + aggregate + head-mean + bias + elu ---------
// One block per dst node. Each wave processes whole edges (full 2KB h row,
// 8 channels/lane -> each lane's channels lie in ONE head: head = lane>>4).
// 4 waves round-robin the edge list; 2 independent online-softmax chains per
// wave => ~8 h-row loads in flight per block. Merge via LDS + shfl butterfly.
__global__ __launch_bounds__(256) void gat_aggregate(const float* __restrict__ h,
                                                     const float* __restrict__ ssrc,
                                                     const float* __restrict__ sdst,
                                                     const int* __restrict__ rowstart,
                                                     const int* __restrict__ csr_src,
                                                     const float* __restrict__ bias,
                                                     float* __restrict__ out,
                                                     int apply_elu) {
  const int n = blockIdx.x;
  const int wave = threadIdx.x >> 6;
  const int lane = threadIdx.x & 63;
  const int hsel = lane >> 4;                  // head owning this lane's channels
  const int rs = rowstart[n], re = rowstart[n + 1];
  const float sdh = sdst[n * HEADS + hsel];
  const float NEG = -1e30f;

  // chain 0: edges rs+wave+8k ; chain 1: edges rs+wave+4+8k
  float m0 = NEG, m1 = NEG, d0 = 0.f, d1 = 0.f;
  float4 p0 = make_float4(0,0,0,0), p1 = make_float4(0,0,0,0);
  float4 q0 = make_float4(0,0,0,0), q1 = make_float4(0,0,0,0);

  for (int j = rs + wave; j < re; j += 8) {
    const int jB = j + 4;
    const float maskB = (jB < re) ? 1.f : 0.f;
    const int sA = csr_src[j];
    const int sB = csr_src[(jB < re) ? jB : j];
    float eA = ssrc[sA * HEADS + hsel] + sdh;
    float eB = ssrc[sB * HEADS + hsel] + sdh;
    eA = (eA > 0.f) ? eA : 0.2f * eA;
    eB = (eB > 0.f) ? eB : 0.2f * eB;
    const float4* hpA = (const float4*)&h[(size_t)sA * HC + lane * 8];
    const float4* hpB = (const float4*)&h[(size_t)sB * HC + lane * 8];
    const float4 hA0 = hpA[0], hA1 = hpA[1];
    const float4 hB0 = hpB[0], hB1 = hpB[1];
    // chain A
    {
      float nm = fmaxf(m0, eA);
      float r = __expf(m0 - nm), w = __expf(eA - nm);
      d0 = d0 * r + w;
      p0.x = fmaf(w, hA0.x, p0.x * r); p0.y = fmaf(w, hA0.y, p0.y * r);
      p0.z = fmaf(w, hA0.z, p0.z * r); p0.w = fmaf(w, hA0.w, p0.w * r);
      q0.x = fmaf(w, hA1.x, q0.x * r); q0.y = fmaf(w, hA1.y, q0.y * r);
      q0.z = fmaf(w, hA1.z, q0.z * r); q0.w = fmaf(w, hA1.w, q0.w * r);
      m0 = nm;
    }
    // chain B (masked tail: raising m1 with a duplicate score is exact; w*0 adds nothing)
    {
      float nm = fmaxf(m1, eB);
      float r = __expf(m1 - nm), w = __expf(eB - nm) * maskB;
      d1 = d1 * r + w;
      p1.x = fmaf(w, hB0.x, p1.x * r); p1.y = fmaf(w, hB0.y, p1.y * r);
      p1.z = fmaf(w, hB0.z, p1.z * r); p1.w = fmaf(w, hB0.w, p1.w * r);
      q1.x = fmaf(w, hB1.x, q1.x * r); q1.y = fmaf(w, hB1.y, q1.y * r);
      q1.z = fmaf(w, hB1.z, q1.z * r); q1.w = fmaf(w, hB1.w, q1.w * r);
      m1 = nm;
    }
  }

  // merge the two chains in-register
  float M = fmaxf(m0, m1);
  float r0 = __expf(m0 - M), r1 = __expf(m1 - M);
  float D = d0 * r0 + d1 * r1;
  float a[8];
  a[0] = p0.x * r0 + p1.x * r1; a[1] = p0.y * r0 + p1.y * r1;
  a[2] = p0.z * r0 + p1.z * r1; a[3] = p0.w * r0 + p1.w * r1;
  a[4] = q0.x * r0 + q1.x * r1; a[5] = q0.y * r0 + q1.y * r1;
  a[6] = q0.z * r0 + q1.z * r1; a[7] = q0.w * r0 + q1.w * r1;

  // merge across 4 waves via LDS
  __shared__ float sm[4][64];
  __shared__ float sdn[4][64];
  __shared__ float sa[4][64][9];   // pad to 9: conflict-free strided reads
  sm[wave][lane] = M;
  sdn[wave][lane] = D;
#pragma unroll
  for (int k = 0; k < 8; ++k) sa[wave][lane][k] = a[k];
  __syncthreads();

  if (wave == 0) {
    float Mg = fmaxf(fmaxf(sm[0][lane], sm[1][lane]), fmaxf(sm[2][lane], sm[3][lane]));
    float Dg = 0.f;
    float g[8] = {};
#pragma unroll
    for (int w = 0; w < 4; ++w) {
      float r = __expf(sm[w][lane] - Mg);
      Dg = fmaf(sdn[w][lane], r, Dg);
#pragma unroll
      for (int k = 0; k < 8; ++k) g[k] = fmaf(sa[w][lane][k], r, g[k]);
    }
    const float inv = 1.f / (Dg + 1e-16f);
#pragma unroll
    for (int k = 0; k < 8; ++k) g[k] *= inv;
    // head mean: combine lanes {l, l^16, l^32, l^48}
#pragma unroll
    for (int k = 0; k < 8; ++k) {
      g[k] += __shfl_xor(g[k], 16);
      g[k] += __shfl_xor(g[k], 32);
    }
    if (lane < 16) {
      const int c0 = lane * 8;
      float v[8];
#pragma unroll
      for (int k = 0; k < 8; ++k) {
        float t = 0.25f * g[k] + bias[c0 + k];
        if (apply_elu) t = (t > 0.f) ? t : expm1f(t);
        v[k] = t;
      }
      *(float4*)&out[(size_t)n * HID + c0]     = make_float4(v[0], v[1], v[2], v[3]);
      *(float4*)&out[(size_t)n * HID + c0 + 4] = make_float4(v[4], v[5], v[6], v[7]);
    }
  }
}

// ---------------- launch ----------------
extern "C" void kernel_launch(void* const* d_in, const int* in_sizes, int n_in,
                              void* d_out, int out_size, void* d_ws, size_t ws_size,
                              hipStream_t stream) {
  const float* x    = (const float*)d_in[0];
  const int*   ei   = (const int*)d_in[1];
  const float* W1   = (const float*)d_in[2];
  const float* as1  = (const float*)d_in[3];
  const float* ad1  = (const float*)d_in[4];
  const float* b1   = (const float*)d_in[5];
  const float* W2   = (const float*)d_in[6];
  const float* as2  = (const float*)d_in[7];
  const float* ad2  = (const float*)d_in[8];
  const float* b2   = (const float*)d_in[9];
  const float* Wout = (const float*)d_in[10];
  const float* bout = (const float*)d_in[11];
  float* out = (float*)d_out;

  const int N = in_sizes[0] / INDIM;   // 20000
  const int E = in_sizes[1] / 2;       // 320000
  const int total = E + N;

  char* p = (char*)d_ws;
  auto alloc = [&](size_t bytes) -> void* {
    void* r = (void*)p;
    p += (bytes + 255) & ~(size_t)255;
    return r;
  };
  float* h     = (float*)alloc((size_t)N * HC * 4);
  float* ssrc  = (float*)alloc((size_t)N * HEADS * 4);
  float* sdst  = (float*)alloc((size_t)N * HEADS * 4);
  float* t1    = (float*)alloc((size_t)N * HID * 4);
  float* t2    = (float*)alloc((size_t)N * HID * 4);
  int* deg     = (int*)alloc((size_t)N * 4);
  int* rowst   = (int*)alloc(((size_t)N + 1) * 4);
  int* cursor  = (int*)alloc((size_t)N * 4);
  int* csr     = (int*)alloc((size_t)total * 4);

  hipMemsetAsync(deg, 0, (size_t)N * 4, stream);
  degree_kernel<<<(total + 255) / 256, 256, 0, stream>>>(ei, E, N, deg);
  scan_kernel<<<1, 1024, 0, stream>>>(deg, rowst, cursor, N);
  scatter_kernel<<<(total + 255) / 256, 256, 0, stream>>>(ei, E, N, cursor, csr);

  dim3 gHC(HC / 64, (N + 63) / 64);
  dim3 gOut(HID / 64, (N + 63) / 64);

  // layer 1
  gemm_f32<<<gHC, 256, 0, stream>>>(x, W1, nullptr, h, N, HC, INDIM);
  scores_kernel<<<N, 256, 0, stream>>>(h, as1, ad1, ssrc, sdst);
  gat_aggregate<<<N, 256, 0, stream>>>(h, ssrc, sdst, rowst, csr, b1, t1, 1);
  // layer 2
  gemm_f32<<<gHC, 256, 0, stream>>>(t1, W2, nullptr, h, N, HC, HID);
  scores_kernel<<<N, 256, 0, stream>>>(h, as2, ad2, ssrc, sdst);
  gat_aggregate<<<N, 256, 0, stream>>>(h, ssrc, sdst, rowst, csr, b2, t2, 1);
  // output projection
  gemm_f32<<<gOut, 256, 0, stream>>>(t2, Wout, bout, out, N, HID, HID);
}

// Round 3
// 338.674 us; speedup vs baseline: 1.2949x; 1.2319x over previous
//
#include <hip/hip_runtime.h>
#include <hip/hip_fp16.h>
#include <math.h>

constexpr int INDIM = 256;
constexpr int HID   = 128;
constexpr int HEADS = 4;
constexpr int HC    = HEADS * HID;   // 512

// ---------------- GEMM (f32 out, final projection): C[M,N] = A@B + bias ----------------
__global__ __launch_bounds__(256) void gemm_f32(const float* __restrict__ A,
                                                const float* __restrict__ B,
                                                const float* __restrict__ bias,
                                                float* __restrict__ C,
                                                int M, int N, int K) {
  __shared__ float As[16][64];
  __shared__ float Bs[16][64];
  const int tid = threadIdx.x;
  const int tx = tid & 15, ty = tid >> 4;
  const int row0 = blockIdx.y * 64, col0 = blockIdx.x * 64;
  float acc[4][4] = {};
  for (int kt = 0; kt < K; kt += 16) {
    {
      int m  = tid >> 2;
      int kg = (tid & 3) * 4;
      int row = row0 + m;
      float4 av = make_float4(0.f, 0.f, 0.f, 0.f);
      if (row < M) av = *(const float4*)&A[(size_t)row * K + kt + kg];
      As[kg + 0][m] = av.x; As[kg + 1][m] = av.y;
      As[kg + 2][m] = av.z; As[kg + 3][m] = av.w;
      int kk = tid >> 4;
      int ng = (tid & 15) * 4;
      float4 bv = *(const float4*)&B[(size_t)(kt + kk) * N + col0 + ng];
      *(float4*)&Bs[kk][ng] = bv;
    }
    __syncthreads();
#pragma unroll
    for (int kk = 0; kk < 16; ++kk) {
      float4 a = *(const float4*)&As[kk][ty * 4];
      float4 b = *(const float4*)&Bs[kk][tx * 4];
      float av[4] = {a.x, a.y, a.z, a.w};
      float bv[4] = {b.x, b.y, b.z, b.w};
#pragma unroll
      for (int i = 0; i < 4; ++i)
#pragma unroll
        for (int j = 0; j < 4; ++j)
          acc[i][j] = fmaf(av[i], bv[j], acc[i][j]);
    }
    __syncthreads();
  }
  float4 bb = make_float4(0.f, 0.f, 0.f, 0.f);
  if (bias) bb = *(const float4*)&bias[col0 + tx * 4];
#pragma unroll
  for (int i = 0; i < 4; ++i) {
    int row = row0 + ty * 4 + i;
    if (row < M) {
      float4 v = make_float4(acc[i][0] + bb.x, acc[i][1] + bb.y,
                             acc[i][2] + bb.z, acc[i][3] + bb.w);
      *(float4*)&C[(size_t)row * N + col0 + tx * 4] = v;
    }
  }
}

// ---------------- GEMM with fp16 output (layer feature matrices) ----------------
__global__ __launch_bounds__(256) void gemm_h16(const float* __restrict__ A,
                                                const float* __restrict__ B,
                                                __half* __restrict__ C,
                                                int M, int N, int K) {
  __shared__ float As[16][64];
  __shared__ float Bs[16][64];
  const int tid = threadIdx.x;
  const int tx = tid & 15, ty = tid >> 4;
  const int row0 = blockIdx.y * 64, col0 = blockIdx.x * 64;
  float acc[4][4] = {};
  for (int kt = 0; kt < K; kt += 16) {
    {
      int m  = tid >> 2;
      int kg = (tid & 3) * 4;
      int row = row0 + m;
      float4 av = make_float4(0.f, 0.f, 0.f, 0.f);
      if (row < M) av = *(const float4*)&A[(size_t)row * K + kt + kg];
      As[kg + 0][m] = av.x; As[kg + 1][m] = av.y;
      As[kg + 2][m] = av.z; As[kg + 3][m] = av.w;
      int kk = tid >> 4;
      int ng = (tid & 15) * 4;
      float4 bv = *(const float4*)&B[(size_t)(kt + kk) * N + col0 + ng];
      *(float4*)&Bs[kk][ng] = bv;
    }
    __syncthreads();
#pragma unroll
    for (int kk = 0; kk < 16; ++kk) {
      float4 a = *(const float4*)&As[kk][ty * 4];
      float4 b = *(const float4*)&Bs[kk][tx * 4];
      float av[4] = {a.x, a.y, a.z, a.w};
      float bv[4] = {b.x, b.y, b.z, b.w};
#pragma unroll
      for (int i = 0; i < 4; ++i)
#pragma unroll
        for (int j = 0; j < 4; ++j)
          acc[i][j] = fmaf(av[i], bv[j], acc[i][j]);
    }
    __syncthreads();
  }
#pragma unroll
  for (int i = 0; i < 4; ++i) {
    int row = row0 + ty * 4 + i;
    if (row < M) {
      __half2 h01 = __float22half2_rn(make_float2(acc[i][0], acc[i][1]));
      __half2 h23 = __float22half2_rn(make_float2(acc[i][2], acc[i][3]));
      uint2 pack = make_uint2(*(unsigned*)&h01, *(unsigned*)&h23);
      *(uint2*)&C[(size_t)row * N + col0 + tx * 4] = pack;
    }
  }
}

// ---------------- per-node attention scores from fp16 features ----------------
__global__ __launch_bounds__(256) void scores_kernel(const __half* __restrict__ h,
                                                     const float* __restrict__ att_src,
                                                     const float* __restrict__ att_dst,
                                                     float* __restrict__ s_src,
                                                     float* __restrict__ s_dst) {
  const int n = blockIdx.x;
  const int wave = threadIdx.x >> 6;
  const int lane = threadIdx.x & 63;
  const float2 hv = __half22float2(*(const __half2*)&h[(size_t)n * HC + wave * HID + lane * 2]);
  const float2 as = *(const float2*)&att_src[wave * HID + lane * 2];
  const float2 ad = *(const float2*)&att_dst[wave * HID + lane * 2];
  float ss = hv.x * as.x + hv.y * as.y;
  float sd = hv.x * ad.x + hv.y * ad.y;
#pragma unroll
  for (int off = 32; off > 0; off >>= 1) {
    ss += __shfl_down(ss, off);
    sd += __shfl_down(sd, off);
  }
  if (lane == 0) {
    s_src[n * HEADS + wave] = ss;
    s_dst[n * HEADS + wave] = sd;
  }
}

// ---------------- CSR build (by dst) ----------------
__global__ void degree_kernel(const int* __restrict__ ei, int E, int N,
                              int* __restrict__ deg) {
  int e = blockIdx.x * blockDim.x + threadIdx.x;
  int total = E + N;
  if (e >= total) return;
  int dst = (e < E) ? ei[E + e] : (e - E);
  atomicAdd(&deg[dst], 1);
}

__global__ __launch_bounds__(1024) void scan_kernel(const int* __restrict__ deg,
                                                    int* __restrict__ rowstart,
                                                    int* __restrict__ cursor, int N) {
  __shared__ int sums[1024];
  const int tid = threadIdx.x;
  const int per = (N + 1023) / 1024;
  int begin = tid * per;
  int end = begin + per; if (end > N) end = N;
  if (begin > N) begin = N;
  int s = 0;
  for (int i = begin; i < end; ++i) s += deg[i];
  sums[tid] = s;
  __syncthreads();
  for (int off = 1; off < 1024; off <<= 1) {
    int v = (tid >= off) ? sums[tid - off] : 0;
    __syncthreads();
    sums[tid] += v;
    __syncthreads();
  }
  int run = (tid == 0) ? 0 : sums[tid - 1];
  for (int i = begin; i < end; ++i) {
    rowstart[i] = run;
    cursor[i] = run;
    run += deg[i];
  }
  if (tid == 1023) rowstart[N] = sums[1023];
}

__global__ void scatter_kernel(const int* __restrict__ ei, int E, int N,
                               int* __restrict__ cursor, int* __restrict__ csr_src) {
  int e = blockIdx.x * blockDim.x + threadIdx.x;
  int total = E + N;
  if (e >= total) return;
  int src, dst;
  if (e < E) { src = ei[e]; dst = ei[E + e]; }
  else       { src = dst = e - E; }
  int pos = atomicAdd(&cursor[dst], 1);
  csr_src[pos] = src;
}

// ---------------- fused segment-softmax + aggregate + head-mean + bias + elu ---------
// One block per dst node; wave handles whole edges (8 fp16 channels/lane = one
// int4 load); head = lane>>4. 4 waves round-robin edges, 2 chains per wave.
__global__ __launch_bounds__(256) void gat_aggregate(const __half* __restrict__ h,
                                                     const float* __restrict__ ssrc,
                                                     const float* __restrict__ sdst,
                                                     const int* __restrict__ rowstart,
                                                     const int* __restrict__ csr_src,
                                                     const float* __restrict__ bias,
                                                     float* __restrict__ out,
                                                     int apply_elu) {
  const int n = blockIdx.x;
  const int wave = threadIdx.x >> 6;
  const int lane = threadIdx.x & 63;
  const int hsel = lane >> 4;
  const int rs = rowstart[n], re = rowstart[n + 1];
  const float sdh = sdst[n * HEADS + hsel];
  const float NEG = -1e30f;

  float m0 = NEG, m1 = NEG, d0 = 0.f, d1 = 0.f;
  float4 p0 = make_float4(0,0,0,0), p1 = make_float4(0,0,0,0);
  float4 q0 = make_float4(0,0,0,0), q1 = make_float4(0,0,0,0);

  for (int j = rs + wave; j < re; j += 8) {
    const int jB = j + 4;
    const float maskB = (jB < re) ? 1.f : 0.f;
    const int sA = csr_src[j];
    const int sB = csr_src[(jB < re) ? jB : j];
    float eA = ssrc[sA * HEADS + hsel] + sdh;
    float eB = ssrc[sB * HEADS + hsel] + sdh;
    eA = (eA > 0.f) ? eA : 0.2f * eA;
    eB = (eB > 0.f) ? eB : 0.2f * eB;
    const int4 rawA = *(const int4*)&h[(size_t)sA * HC + lane * 8];
    const int4 rawB = *(const int4*)&h[(size_t)sB * HC + lane * 8];
    const __half2* phA = (const __half2*)&rawA;
    const __half2* phB = (const __half2*)&rawB;
    // chain A
    {
      float2 f0 = __half22float2(phA[0]), f1 = __half22float2(phA[1]);
      float2 f2 = __half22float2(phA[2]), f3 = __half22float2(phA[3]);
      float nm = fmaxf(m0, eA);
      float r = __expf(m0 - nm), w = __expf(eA - nm);
      d0 = d0 * r + w;
      p0.x = fmaf(w, f0.x, p0.x * r); p0.y = fmaf(w, f0.y, p0.y * r);
      p0.z = fmaf(w, f1.x, p0.z * r); p0.w = fmaf(w, f1.y, p0.w * r);
      q0.x = fmaf(w, f2.x, q0.x * r); q0.y = fmaf(w, f2.y, q0.y * r);
      q0.z = fmaf(w, f3.x, q0.z * r); q0.w = fmaf(w, f3.y, q0.w * r);
      m0 = nm;
    }
    // chain B (masked tail)
    {
      float2 f0 = __half22float2(phB[0]), f1 = __half22float2(phB[1]);
      float2 f2 = __half22float2(phB[2]), f3 = __half22float2(phB[3]);
      float nm = fmaxf(m1, eB);
      float r = __expf(m1 - nm), w = __expf(eB - nm) * maskB;
      d1 = d1 * r + w;
      p1.x = fmaf(w, f0.x, p1.x * r); p1.y = fmaf(w, f0.y, p1.y * r);
      p1.z = fmaf(w, f1.x, p1.z * r); p1.w = fmaf(w, f1.y, p1.w * r);
      q1.x = fmaf(w, f2.x, q1.x * r); q1.y = fmaf(w, f2.y, q1.y * r);
      q1.z = fmaf(w, f3.x, q1.z * r); q1.w = fmaf(w, f3.y, q1.w * r);
      m1 = nm;
    }
  }

  float M = fmaxf(m0, m1);
  float r0 = __expf(m0 - M), r1 = __expf(m1 - M);
  float D = d0 * r0 + d1 * r1;
  float a[8];
  a[0] = p0.x * r0 + p1.x * r1; a[1] = p0.y * r0 + p1.y * r1;
  a[2] = p0.z * r0 + p1.z * r1; a[3] = p0.w * r0 + p1.w * r1;
  a[4] = q0.x * r0 + q1.x * r1; a[5] = q0.y * r0 + q1.y * r1;
  a[6] = q0.z * r0 + q1.z * r1; a[7] = q0.w * r0 + q1.w * r1;

  __shared__ float sm[4][64];
  __shared__ float sdn[4][64];
  __shared__ float sa[4][64][9];
  sm[wave][lane] = M;
  sdn[wave][lane] = D;
#pragma unroll
  for (int k = 0; k < 8; ++k) sa[wave][lane][k] = a[k];
  __syncthreads();

  if (wave == 0) {
    float Mg = fmaxf(fmaxf(sm[0][lane], sm[1][lane]), fmaxf(sm[2][lane], sm[3][lane]));
    float Dg = 0.f;
    float g[8] = {};
#pragma unroll
    for (int w = 0; w < 4; ++w) {
      float r = __expf(sm[w][lane] - Mg);
      Dg = fmaf(sdn[w][lane], r, Dg);
#pragma unroll
      for (int k = 0; k < 8; ++k) g[k] = fmaf(sa[w][lane][k], r, g[k]);
    }
    const float inv = 1.f / (Dg + 1e-16f);
#pragma unroll
    for (int k = 0; k < 8; ++k) g[k] *= inv;
#pragma unroll
    for (int k = 0; k < 8; ++k) {
      g[k] += __shfl_xor(g[k], 16);
      g[k] += __shfl_xor(g[k], 32);
    }
    if (lane < 16) {
      const int c0 = lane * 8;
      float v[8];
#pragma unroll
      for (int k = 0; k < 8; ++k) {
        float t = 0.25f * g[k] + bias[c0 + k];
        if (apply_elu) t = (t > 0.f) ? t : expm1f(t);
        v[k] = t;
      }
      *(float4*)&out[(size_t)n * HID + c0]     = make_float4(v[0], v[1], v[2], v[3]);
      *(float4*)&out[(size_t)n * HID + c0 + 4] = make_float4(v[4], v[5], v[6], v[7]);
    }
  }
}

// ---------------- launch ----------------
extern "C" void kernel_launch(void* const* d_in, const int* in_sizes, int n_in,
                              void* d_out, int out_size, void* d_ws, size_t ws_size,
                              hipStream_t stream) {
  const float* x    = (const float*)d_in[0];
  const int*   ei   = (const int*)d_in[1];
  const float* W1   = (const float*)d_in[2];
  const float* as1  = (const float*)d_in[3];
  const float* ad1  = (const float*)d_in[4];
  const float* b1   = (const float*)d_in[5];
  const float* W2   = (const float*)d_in[6];
  const float* as2  = (const float*)d_in[7];
  const float* ad2  = (const float*)d_in[8];
  const float* b2   = (const float*)d_in[9];
  const float* Wout = (const float*)d_in[10];
  const float* bout = (const float*)d_in[11];
  float* out = (float*)d_out;

  const int N = in_sizes[0] / INDIM;   // 20000
  const int E = in_sizes[1] / 2;       // 320000
  const int total = E + N;

  char* p = (char*)d_ws;
  auto alloc = [&](size_t bytes) -> void* {
    void* r = (void*)p;
    p += (bytes + 255) & ~(size_t)255;
    return r;
  };
  __half* h16  = (__half*)alloc((size_t)N * HC * 2);      // 20.5 MB
  float* ssrc  = (float*)alloc((size_t)N * HEADS * 4);
  float* sdst  = (float*)alloc((size_t)N * HEADS * 4);
  float* t1    = (float*)alloc((size_t)N * HID * 4);
  float* t2    = (float*)alloc((size_t)N * HID * 4);
  int* deg     = (int*)alloc((size_t)N * 4);
  int* rowst   = (int*)alloc(((size_t)N + 1) * 4);
  int* cursor  = (int*)alloc((size_t)N * 4);
  int* csr     = (int*)alloc((size_t)total * 4);

  hipMemsetAsync(deg, 0, (size_t)N * 4, stream);
  degree_kernel<<<(total + 255) / 256, 256, 0, stream>>>(ei, E, N, deg);
  scan_kernel<<<1, 1024, 0, stream>>>(deg, rowst, cursor, N);
  scatter_kernel<<<(total + 255) / 256, 256, 0, stream>>>(ei, E, N, cursor, csr);

  dim3 gHC(HC / 64, (N + 63) / 64);
  dim3 gOut(HID / 64, (N + 63) / 64);

  // layer 1
  gemm_h16<<<gHC, 256, 0, stream>>>(x, W1, h16, N, HC, INDIM);
  scores_kernel<<<N, 256, 0, stream>>>(h16, as1, ad1, ssrc, sdst);
  gat_aggregate<<<N, 256, 0, stream>>>(h16, ssrc, sdst, rowst, csr, b1, t1, 1);
  // layer 2
  gemm_h16<<<gHC, 256, 0, stream>>>(t1, W2, h16, N, HC, HID);
  scores_kernel<<<N, 256, 0, stream>>>(h16, as2, ad2, ssrc, sdst);
  gat_aggregate<<<N, 256, 0, stream>>>(h16, ssrc, sdst, rowst, csr, b2, t2, 1);
  // output projection
  gemm_f32<<<gOut, 256, 0, stream>>>(t2, Wout, bout, out, N, HID, HID);
}

// Round 4
// 256.977 us; speedup vs baseline: 1.7065x; 1.3179x over previous
//
#include <hip/hip_runtime.h>
#include <hip/hip_fp16.h>
#include <math.h>

constexpr int INDIM = 256;
constexpr int HID   = 128;
constexpr int HEADS = 4;
constexpr int HC    = HEADS * HID;   // 512

typedef __attribute__((ext_vector_type(8))) _Float16 f16x8;
typedef __attribute__((ext_vector_type(4))) float    f32x4;

#define GLOAD_LDS16(gsrc, ldst)                                                        \
  __builtin_amdgcn_global_load_lds((const __attribute__((address_space(1))) void*)(gsrc), \
                                   (__attribute__((address_space(3))) void*)(ldst), 16, 0, 0)

// ---------------- MFMA f16 GEMM: C[M,N] = A[M,K] @ BT[N,K]^T ----------------
// 128x64 tile, BK=32, 4 waves. global_load_lds staging with XOR-swizzled 16B
// units (linear LDS dest + inverse-swizzled global src; swizzled ds_read_b128).
// Fragment: lane l -> A[m=l&15][k=(l>>4)*8+j]; C/D: col=l&15, row=(l>>4)*4+r.
__global__ __launch_bounds__(256) void gemm_f16_mfma(const __half* __restrict__ A,
                                                     const __half* __restrict__ BT,
                                                     float* __restrict__ Cf,
                                                     __half* __restrict__ Ch,
                                                     const float* __restrict__ bias,
                                                     int M, int N, int K) {
  __shared__ _Float16 Asm[128 * 32];   // 8 KB, rows of 32 f16 (64 B)
  __shared__ _Float16 Bsm[64 * 32];    // 4 KB
  const int tid = threadIdx.x;
  const int w = tid >> 6, l = tid & 63;
  const int wr = w >> 1, wc = w & 1;
  const int row0 = blockIdx.y * 128, col0 = blockIdx.x * 64;

  // staging: lane's slot (m=R0+(l>>2), kq'=l&3) must hold global k-unit kq'^swz(m)
  const int src_kq   = (l & 3) ^ ((l >> 2) & 3) ^ ((l >> 4) & 3);
  // read: fragment k-unit (l>>4) lives at swizzled unit (l>>4)^swz(m), swz(m)=(l&3)^((l>>2)&3)
  const int read_off = (((l >> 4) ^ (l & 3) ^ ((l >> 2) & 3)) * 8);

  f32x4 acc[4][2] = {};

  for (int kt = 0; kt < K; kt += 32) {
    // stage A: 8 chunks x 16 rows (1 KB each); wave w stages chunks 2w, 2w+1
#pragma unroll
    for (int c = 0; c < 2; ++c) {
      const int R0 = w * 32 + c * 16;
      int row = row0 + R0 + (l >> 2);
      if (row >= M) row = M - 1;
      GLOAD_LDS16(&A[(size_t)row * K + kt + src_kq * 8], &Asm[R0 * 32]);
    }
    // stage B: 4 chunks x 16 rows; wave w stages chunk w  (N multiple of 64)
    {
      const int R0 = w * 16;
      const int row = col0 + R0 + (l >> 2);
      GLOAD_LDS16(&BT[(size_t)row * K + kt + src_kq * 8], &Bsm[R0 * 32]);
    }
    __syncthreads();

    f16x8 bfr[2];
#pragma unroll
    for (int nf = 0; nf < 2; ++nf) {
      const int nl = wc * 32 + nf * 16 + (l & 15);
      bfr[nf] = *(const f16x8*)&Bsm[nl * 32 + read_off];
    }
#pragma unroll
    for (int mf = 0; mf < 4; ++mf) {
      const int ml = wr * 64 + mf * 16 + (l & 15);
      const f16x8 afr = *(const f16x8*)&Asm[ml * 32 + read_off];
#pragma unroll
      for (int nf = 0; nf < 2; ++nf)
        acc[mf][nf] = __builtin_amdgcn_mfma_f32_16x16x32_f16(afr, bfr[nf], acc[mf][nf], 0, 0, 0);
    }
    __syncthreads();
  }

  // epilogue
#pragma unroll
  for (int mf = 0; mf < 4; ++mf) {
#pragma unroll
    for (int r = 0; r < 4; ++r) {
      const int row = row0 + wr * 64 + mf * 16 + (l >> 4) * 4 + r;
      if (row < M) {
#pragma unroll
        for (int nf = 0; nf < 2; ++nf) {
          const int col = col0 + wc * 32 + nf * 16 + (l & 15);
          const float v = acc[mf][nf][r];
          if (Ch) Ch[(size_t)row * N + col] = __float2half(v);
          else    Cf[(size_t)row * N + col] = v + (bias ? bias[col] : 0.f);
        }
      }
    }
  }
}

// ---------------- prep: f32 -> f16 convert / transpose ----------------
__global__ void cvt_f32_to_f16(const float* __restrict__ in, __half* __restrict__ out, int n) {
  const int i = (blockIdx.x * blockDim.x + threadIdx.x) * 4;
  if (i + 3 < n) {
    float4 v = *(const float4*)&in[i];
    __half2 a = __float22half2_rn(make_float2(v.x, v.y));
    __half2 b = __float22half2_rn(make_float2(v.z, v.w));
    *(uint2*)&out[i] = make_uint2(*(unsigned*)&a, *(unsigned*)&b);
  }
}

// WT[n*K + k] = (f16) W[k*N + n]
__global__ void transpose_to_f16(const float* __restrict__ W, __half* __restrict__ WT,
                                 int K, int N) {
  const int idx = blockIdx.x * blockDim.x + threadIdx.x;
  if (idx >= K * N) return;
  const int n = idx / K, k = idx % K;
  WT[idx] = __float2half(W[(size_t)k * N + n]);
}

// ---------------- per-node attention scores from fp16 features ----------------
__global__ __launch_bounds__(256) void scores_kernel(const __half* __restrict__ h,
                                                     const float* __restrict__ att_src,
                                                     const float* __restrict__ att_dst,
                                                     float* __restrict__ s_src,
                                                     float* __restrict__ s_dst) {
  const int n = blockIdx.x;
  const int wave = threadIdx.x >> 6;
  const int lane = threadIdx.x & 63;
  const float2 hv = __half22float2(*(const __half2*)&h[(size_t)n * HC + wave * HID + lane * 2]);
  const float2 as = *(const float2*)&att_src[wave * HID + lane * 2];
  const float2 ad = *(const float2*)&att_dst[wave * HID + lane * 2];
  float ss = hv.x * as.x + hv.y * as.y;
  float sd = hv.x * ad.x + hv.y * ad.y;
#pragma unroll
  for (int off = 32; off > 0; off >>= 1) {
    ss += __shfl_down(ss, off);
    sd += __shfl_down(sd, off);
  }
  if (lane == 0) {
    s_src[n * HEADS + wave] = ss;
    s_dst[n * HEADS + wave] = sd;
  }
}

// ---------------- CSR build (by dst) ----------------
__global__ void degree_kernel(const int* __restrict__ ei, int E, int N,
                              int* __restrict__ deg) {
  int e = blockIdx.x * blockDim.x + threadIdx.x;
  int total = E + N;
  if (e >= total) return;
  int dst = (e < E) ? ei[E + e] : (e - E);
  atomicAdd(&deg[dst], 1);
}

__global__ __launch_bounds__(1024) void scan_kernel(const int* __restrict__ deg,
                                                    int* __restrict__ rowstart,
                                                    int* __restrict__ cursor, int N) {
  __shared__ int sums[1024];
  const int tid = threadIdx.x;
  const int per = (N + 1023) / 1024;
  int begin = tid * per;
  int end = begin + per; if (end > N) end = N;
  if (begin > N) begin = N;
  int s = 0;
  for (int i = begin; i < end; ++i) s += deg[i];
  sums[tid] = s;
  __syncthreads();
  for (int off = 1; off < 1024; off <<= 1) {
    int v = (tid >= off) ? sums[tid - off] : 0;
    __syncthreads();
    sums[tid] += v;
    __syncthreads();
  }
  int run = (tid == 0) ? 0 : sums[tid - 1];
  for (int i = begin; i < end; ++i) {
    rowstart[i] = run;
    cursor[i] = run;
    run += deg[i];
  }
  if (tid == 1023) rowstart[N] = sums[1023];
}

__global__ void scatter_kernel(const int* __restrict__ ei, int E, int N,
                               int* __restrict__ cursor, int* __restrict__ csr_src) {
  int e = blockIdx.x * blockDim.x + threadIdx.x;
  int total = E + N;
  if (e >= total) return;
  int src, dst;
  if (e < E) { src = ei[e]; dst = ei[E + e]; }
  else       { src = dst = e - E; }
  int pos = atomicAdd(&cursor[dst], 1);
  csr_src[pos] = src;
}

// ---------------- fused segment-softmax + aggregate + head-mean + bias + elu ---------
// fp16 in (gather), fp16 out (feeds next MFMA GEMM). f32 accumulation.
__global__ __launch_bounds__(256) void gat_aggregate(const __half* __restrict__ h,
                                                     const float* __restrict__ ssrc,
                                                     const float* __restrict__ sdst,
                                                     const int* __restrict__ rowstart,
                                                     const int* __restrict__ csr_src,
                                                     const float* __restrict__ bias,
                                                     __half* __restrict__ out,
                                                     int apply_elu) {
  const int n = blockIdx.x;
  const int wave = threadIdx.x >> 6;
  const int lane = threadIdx.x & 63;
  const int hsel = lane >> 4;
  const int rs = rowstart[n], re = rowstart[n + 1];
  const float sdh = sdst[n * HEADS + hsel];
  const float NEG = -1e30f;

  float m0 = NEG, m1 = NEG, d0 = 0.f, d1 = 0.f;
  float4 p0 = make_float4(0,0,0,0), p1 = make_float4(0,0,0,0);
  float4 q0 = make_float4(0,0,0,0), q1 = make_float4(0,0,0,0);

  for (int j = rs + wave; j < re; j += 8) {
    const int jB = j + 4;
    const float maskB = (jB < re) ? 1.f : 0.f;
    const int sA = csr_src[j];
    const int sB = csr_src[(jB < re) ? jB : j];
    float eA = ssrc[sA * HEADS + hsel] + sdh;
    float eB = ssrc[sB * HEADS + hsel] + sdh;
    eA = (eA > 0.f) ? eA : 0.2f * eA;
    eB = (eB > 0.f) ? eB : 0.2f * eB;
    const int4 rawA = *(const int4*)&h[(size_t)sA * HC + lane * 8];
    const int4 rawB = *(const int4*)&h[(size_t)sB * HC + lane * 8];
    const __half2* phA = (const __half2*)&rawA;
    const __half2* phB = (const __half2*)&rawB;
    {
      float2 f0 = __half22float2(phA[0]), f1 = __half22float2(phA[1]);
      float2 f2 = __half22float2(phA[2]), f3 = __half22float2(phA[3]);
      float nm = fmaxf(m0, eA);
      float r = __expf(m0 - nm), wgt = __expf(eA - nm);
      d0 = d0 * r + wgt;
      p0.x = fmaf(wgt, f0.x, p0.x * r); p0.y = fmaf(wgt, f0.y, p0.y * r);
      p0.z = fmaf(wgt, f1.x, p0.z * r); p0.w = fmaf(wgt, f1.y, p0.w * r);
      q0.x = fmaf(wgt, f2.x, q0.x * r); q0.y = fmaf(wgt, f2.y, q0.y * r);
      q0.z = fmaf(wgt, f3.x, q0.z * r); q0.w = fmaf(wgt, f3.y, q0.w * r);
      m0 = nm;
    }
    {
      float2 f0 = __half22float2(phB[0]), f1 = __half22float2(phB[1]);
      float2 f2 = __half22float2(phB[2]), f3 = __half22float2(phB[3]);
      float nm = fmaxf(m1, eB);
      float r = __expf(m1 - nm), wgt = __expf(eB - nm) * maskB;
      d1 = d1 * r + wgt;
      p1.x = fmaf(wgt, f0.x, p1.x * r); p1.y = fmaf(wgt, f0.y, p1.y * r);
      p1.z = fmaf(wgt, f1.x, p1.z * r); p1.w = fmaf(wgt, f1.y, p1.w * r);
      q1.x = fmaf(wgt, f2.x, q1.x * r); q1.y = fmaf(wgt, f2.y, q1.y * r);
      q1.z = fmaf(wgt, f3.x, q1.z * r); q1.w = fmaf(wgt, f3.y, q1.w * r);
      m1 = nm;
    }
  }

  float M = fmaxf(m0, m1);
  float r0 = __expf(m0 - M), r1 = __expf(m1 - M);
  float D = d0 * r0 + d1 * r1;
  float a[8];
  a[0] = p0.x * r0 + p1.x * r1; a[1] = p0.y * r0 + p1.y * r1;
  a[2] = p0.z * r0 + p1.z * r1; a[3] = p0.w * r0 + p1.w * r1;
  a[4] = q0.x * r0 + q1.x * r1; a[5] = q0.y * r0 + q1.y * r1;
  a[6] = q0.z * r0 + q1.z * r1; a[7] = q0.w * r0 + q1.w * r1;

  __shared__ float sm[4][64];
  __shared__ float sdn[4][64];
  __shared__ float sa[4][64][9];
  sm[wave][lane] = M;
  sdn[wave][lane] = D;
#pragma unroll
  for (int k = 0; k < 8; ++k) sa[wave][lane][k] = a[k];
  __syncthreads();

  if (wave == 0) {
    float Mg = fmaxf(fmaxf(sm[0][lane], sm[1][lane]), fmaxf(sm[2][lane], sm[3][lane]));
    float Dg = 0.f;
    float g[8] = {};
#pragma unroll
    for (int wv = 0; wv < 4; ++wv) {
      float r = __expf(sm[wv][lane] - Mg);
      Dg = fmaf(sdn[wv][lane], r, Dg);
#pragma unroll
      for (int k = 0; k < 8; ++k) g[k] = fmaf(sa[wv][lane][k], r, g[k]);
    }
    const float inv = 1.f / (Dg + 1e-16f);
#pragma unroll
    for (int k = 0; k < 8; ++k) g[k] *= inv;
#pragma unroll
    for (int k = 0; k < 8; ++k) {
      g[k] += __shfl_xor(g[k], 16);
      g[k] += __shfl_xor(g[k], 32);
    }
    if (lane < 16) {
      const int c0 = lane * 8;
      __half hv[8];
#pragma unroll
      for (int k = 0; k < 8; ++k) {
        float t = 0.25f * g[k] + bias[c0 + k];
        if (apply_elu) t = (t > 0.f) ? t : expm1f(t);
        hv[k] = __float2half(t);
      }
      *(int4*)&out[(size_t)n * HID + c0] = *(int4*)hv;
    }
  }
}

// ---------------- launch ----------------
extern "C" void kernel_launch(void* const* d_in, const int* in_sizes, int n_in,
                              void* d_out, int out_size, void* d_ws, size_t ws_size,
                              hipStream_t stream) {
  const float* x    = (const float*)d_in[0];
  const int*   ei   = (const int*)d_in[1];
  const float* W1   = (const float*)d_in[2];
  const float* as1  = (const float*)d_in[3];
  const float* ad1  = (const float*)d_in[4];
  const float* b1   = (const float*)d_in[5];
  const float* W2   = (const float*)d_in[6];
  const float* as2  = (const float*)d_in[7];
  const float* ad2  = (const float*)d_in[8];
  const float* b2   = (const float*)d_in[9];
  const float* Wout = (const float*)d_in[10];
  const float* bout = (const float*)d_in[11];
  float* out = (float*)d_out;

  const int N = in_sizes[0] / INDIM;   // 20000
  const int E = in_sizes[1] / 2;       // 320000
  const int total = E + N;

  char* p = (char*)d_ws;
  auto alloc = [&](size_t bytes) -> void* {
    void* r = (void*)p;
    p += (bytes + 255) & ~(size_t)255;
    return r;
  };
  __half* x16  = (__half*)alloc((size_t)N * INDIM * 2);   // 10.2 MB
  __half* h16  = (__half*)alloc((size_t)N * HC * 2);      // 20.5 MB
  __half* t1h  = (__half*)alloc((size_t)N * HID * 2);
  __half* t2h  = (__half*)alloc((size_t)N * HID * 2);
  __half* w1t  = (__half*)alloc((size_t)INDIM * HC * 2);  // [512][256]
  __half* w2t  = (__half*)alloc((size_t)HID * HC * 2);    // [512][128]
  __half* wot  = (__half*)alloc((size_t)HID * HID * 2);   // [128][128]
  float* ssrc  = (float*)alloc((size_t)N * HEADS * 4);
  float* sdst  = (float*)alloc((size_t)N * HEADS * 4);
  int* deg     = (int*)alloc((size_t)N * 4);
  int* rowst   = (int*)alloc(((size_t)N + 1) * 4);
  int* cursor  = (int*)alloc((size_t)N * 4);
  int* csr     = (int*)alloc((size_t)total * 4);

  // prep: fp16 conversions (+ weight transposes to [N][K])
  cvt_f32_to_f16<<<(N * INDIM / 4 + 255) / 256, 256, 0, stream>>>(x, x16, N * INDIM);
  transpose_to_f16<<<(INDIM * HC + 255) / 256, 256, 0, stream>>>(W1, w1t, INDIM, HC);
  transpose_to_f16<<<(HID * HC + 255) / 256, 256, 0, stream>>>(W2, w2t, HID, HC);
  transpose_to_f16<<<(HID * HID + 255) / 256, 256, 0, stream>>>(Wout, wot, HID, HID);

  // CSR build
  hipMemsetAsync(deg, 0, (size_t)N * 4, stream);
  degree_kernel<<<(total + 255) / 256, 256, 0, stream>>>(ei, E, N, deg);
  scan_kernel<<<1, 1024, 0, stream>>>(deg, rowst, cursor, N);
  scatter_kernel<<<(total + 255) / 256, 256, 0, stream>>>(ei, E, N, cursor, csr);

  const int mblk = (N + 127) / 128;
  // layer 1: h = x @ W1   [20000,256]x[256,512]
  gemm_f16_mfma<<<dim3(HC / 64, mblk), 256, 0, stream>>>(x16, w1t, nullptr, h16, nullptr, N, HC, INDIM);
  scores_kernel<<<N, 256, 0, stream>>>(h16, as1, ad1, ssrc, sdst);
  gat_aggregate<<<N, 256, 0, stream>>>(h16, ssrc, sdst, rowst, csr, b1, t1h, 1);
  // layer 2: h = t1 @ W2  [20000,128]x[128,512]
  gemm_f16_mfma<<<dim3(HC / 64, mblk), 256, 0, stream>>>(t1h, w2t, nullptr, h16, nullptr, N, HC, HID);
  scores_kernel<<<N, 256, 0, stream>>>(h16, as2, ad2, ssrc, sdst);
  gat_aggregate<<<N, 256, 0, stream>>>(h16, ssrc, sdst, rowst, csr, b2, t2h, 1);
  // output projection: out = t2 @ W_out + bout  [20000,128]x[128,128], f32 out
  gemm_f16_mfma<<<dim3(HID / 64, mblk), 256, 0, stream>>>(t2h, wot, out, nullptr, bout, N, HID, HID);
}